// Round 15
// baseline (754.187 us; speedup 1.0000x reference)
//
#include <hip/hip_runtime.h>

#define DEVI __device__ __forceinline__

typedef __attribute__((ext_vector_type(8))) __bf16 bf16x8;
typedef __attribute__((ext_vector_type(4))) float f32x4;
typedef __attribute__((ext_vector_type(16))) float f32x16;
typedef __attribute__((ext_vector_type(4))) unsigned uint32x4;

DEVI __bf16 f2bf(float f) {
  unsigned u = __builtin_bit_cast(unsigned, f);
  unsigned r = u + 0x7fffu + ((u >> 16) & 1u);
  unsigned short h = (unsigned short)(r >> 16);
  return __builtin_bit_cast(__bf16, h);
}

DEVI unsigned cvt_pk_bf16(float lo, float hi) {
  unsigned r;
  asm("v_cvt_pk_bf16_f32 %0, %1, %2" : "=v"(r) : "v"(lo), "v"(hi));
  return r;
}

DEVI void load_lds16(const void* g, void* l) {
  __builtin_amdgcn_global_load_lds((__attribute__((address_space(1))) const void*)g,
                                   (__attribute__((address_space(3))) void*)l,
                                   16, 0, 0);
}

// all four 1024x1024 weight matrices in one launch
__global__ void convert_w4(const float* __restrict__ w0, const float* __restrict__ w1,
                           const float* __restrict__ w2, const float* __restrict__ w3,
                           __bf16* __restrict__ o0, __bf16* __restrict__ o1,
                           __bf16* __restrict__ o2, __bf16* __restrict__ o3, int n8) {
  int stride = gridDim.x * blockDim.x;
  for (int i = blockIdx.x * blockDim.x + threadIdx.x; i < 4 * n8; i += stride) {
    int sel = i / n8, j = i - sel * n8;
    const float* in = sel == 0 ? w0 : sel == 1 ? w1 : sel == 2 ? w2 : w3;
    __bf16* out = sel == 0 ? o0 : sel == 1 ? o1 : sel == 2 ? o2 : o3;
    float4 a = ((const float4*)in)[j * 2];
    float4 b = ((const float4*)in)[j * 2 + 1];
    bf16x8 o;
    o[0] = f2bf(a.x); o[1] = f2bf(a.y); o[2] = f2bf(a.z); o[3] = f2bf(a.w);
    o[4] = f2bf(b.x); o[5] = f2bf(b.y); o[6] = f2bf(b.z); o[7] = f2bf(b.w);
    ((bf16x8*)out)[j] = o;
  }
}

// ---------------------------------------------------------------------------
// FUSED QKV projection GEMM (round-8/14 proven structure). ONLY CHANGE THIS
// ROUND: __launch_bounds__(256,3) -> (256,5). Kernel uses 32KB LDS + 68 VGPR,
// so LDS admits 5 blocks/CU (160/32) and VGPR fits the 512/5=102 cap; the old
// bound artificially pinned residency at 3 blocks (12 waves/CU) on a
// latency-bound kernel (MfmaUtil 13.5 / VALUBusy 11.8 / Occ 29%).
// A fp32 -> regs (float4 loads issued after the barrier, latency hides under
// compute) -> cvt_pk -> swizzled ds_write; W via global_load_lds.
// SEL 0: Qh bf16 [BH][S][64], PRE-SCALED by CE. SEL 1: Kh. SEL 2: Vt [BH][64][S].
// ---------------------------------------------------------------------------
__global__ __launch_bounds__(256, 5) void gemm_qkv(
    const float* __restrict__ qa, const float* __restrict__ ka, const float* __restrict__ va,
    const __bf16* __restrict__ Wq, const __bf16* __restrict__ Wk, const __bf16* __restrict__ Wv,
    const float* __restrict__ bq, const float* __restrict__ bk, const float* __restrict__ bv,
    __bf16* __restrict__ Qh, __bf16* __restrict__ Kh, __bf16* __restrict__ Vt)
{
  __shared__ __align__(16) __bf16 As[2][128 * 32];
  __shared__ __align__(16) __bf16 Bs[2][128 * 32];
  const int sel = blockIdx.z;
  const float* A = sel == 0 ? qa : sel == 1 ? ka : va;
  const __bf16* W = sel == 0 ? Wq : sel == 1 ? Wk : Wv;
  const float* bias = sel == 0 ? bq : sel == 1 ? bk : bv;
  __bf16* outp = sel == 0 ? Qh : sel == 1 ? Kh : Vt;
  const bool vmode = (sel == 2);
  const float osc = (sel == 0) ? 0.18033688f : 1.0f; // CE = (1/8)*log2(e) into Q

  const int tid = threadIdx.x;
  const int lane = tid & 63;
  const int ln = lane & 15, g = lane >> 4;
  const int w = tid >> 6;
  const int wr = w >> 1, wc = w & 1;
  const int id = blockIdx.y * 64 + blockIdx.x;
  const int bx = 8 * (id & 7) + ((id >> 3) & 7);     // XCD swizzle
  const int by = id >> 6;
  const int row0 = bx * 128, col0 = by * 128;

  const int ar = tid >> 1, ah = tid & 1;   // A staging: row (0..127), half (16 floats)
  const int axr = (ar >> 1) & 3;           // row swizzle term

  f32x4 acc[4][4] = {};
  float4 fA[4];

  auto issueA = [&](int kt) {              // 64B fp32 per thread -> regs
    const float4* src = (const float4*)&A[(size_t)(row0 + ar) * 1024 + kt * 32 + ah * 16];
#pragma unroll
    for (int j = 0; j < 4; ++j) fA[j] = src[j];
  };
  auto issueW = [&](int buf, int kt) {     // 2x gload_lds per thread
#pragma unroll
    for (int i = 0; i < 2; ++i) {
      int c = tid + 256 * i;
      int r = c >> 2, sl = c & 3;
      int so = 8 * (sl ^ ((r >> 1) & 3));  // inverse-swizzled source slot
      load_lds16(&W[(size_t)(col0 + r) * 1024 + kt * 32 + so], &Bs[buf][c * 8]);
    }
  };
  auto writeA = [&](int buf) {             // cvt + swizzled ds_write_b128 x2
#pragma unroll
    for (int j = 0; j < 2; ++j) {
      uint32x4 o;
      o[0] = cvt_pk_bf16(fA[2 * j].x, fA[2 * j].y);
      o[1] = cvt_pk_bf16(fA[2 * j].z, fA[2 * j].w);
      o[2] = cvt_pk_bf16(fA[2 * j + 1].x, fA[2 * j + 1].y);
      o[3] = cvt_pk_bf16(fA[2 * j + 1].z, fA[2 * j + 1].w);
      int s = 2 * ah + j;                  // source 16B slot
      *(uint32x4*)&As[buf][ar * 32 + (s ^ axr) * 8] = o;   // LDS slot = s ^ x
    }
  };
  auto compute = [&](int buf) {
    const __bf16* as = As[buf];
    const __bf16* bs = Bs[buf];
    bf16x8 aF[4], bF[4];
#pragma unroll
    for (int mi = 0; mi < 4; ++mi) {
      int r = wr * 64 + mi * 16 + ln;
      aF[mi] = *(const bf16x8*)&as[r * 32 + ((g * 8) ^ (((r >> 1) & 3) * 8))];
    }
#pragma unroll
    for (int ni = 0; ni < 4; ++ni) {
      int r = wc * 64 + ni * 16 + ln;
      bF[ni] = *(const bf16x8*)&bs[r * 32 + ((g * 8) ^ (((r >> 1) & 3) * 8))];
    }
    __builtin_amdgcn_s_setprio(1);
#pragma unroll
    for (int mi = 0; mi < 4; ++mi)
#pragma unroll
      for (int ni = 0; ni < 4; ++ni)
        acc[mi][ni] = __builtin_amdgcn_mfma_f32_16x16x32_bf16(aF[mi], bF[ni], acc[mi][ni], 0, 0, 0);
    __builtin_amdgcn_s_setprio(0);
  };

  // prologue: stage tile 0
  issueA(0); issueW(0, 0);
  writeA(0);                               // compiler waits for fA loads
  __syncthreads();                         // drains W(0) gload_lds, publishes buf0
#pragma unroll 1
  for (int kt = 0; kt < 32; ++kt) {
    const int cur = kt & 1, nxt = cur ^ 1;
    if (kt + 1 < 32) { issueA(kt + 1); issueW(nxt, kt + 1); }   // latency under compute
    compute(cur);
    if (kt + 1 < 32) writeA(nxt);          // regs -> LDS (other buffer)
    __syncthreads();                       // drain + publish buf nxt
  }

#pragma unroll
  for (int ni = 0; ni < 4; ++ni) {
    int n = col0 + wc * 64 + ni * 16 + ln;
    float bv = bias[n];
#pragma unroll
    for (int mi = 0; mi < 4; ++mi) {
#pragma unroll
      for (int i = 0; i < 4; ++i) {
        int m = row0 + wr * 64 + mi * 16 + g * 4 + i;   // C-layout: row=(l>>4)*4+i, col=l&15
        float val = (acc[mi][ni][i] + bv) * osc;
        int b = m >> 11, s = m & 2047, h = n >> 6, d = n & 63;
        size_t idx = vmode
          ? ((size_t)((b * 16 + h) * 64 + d) * 2048 + s)
          : ((size_t)((b * 16 + h) * 2048 + s) * 64 + d);
        outp[idx] = f2bf(val);
      }
    }
  }
}

// ---------------------------------------------------------------------------
// Output GEMM (bf16 A = Ctx): depth-2 counted-vmcnt, fp32 out.
// ONLY CHANGE: __launch_bounds__(256,2) -> (256,3) (48KB LDS admits 3/CU).
// ---------------------------------------------------------------------------
__global__ __launch_bounds__(256, 3) void gemm_out(
    const __bf16* __restrict__ A, const __bf16* __restrict__ W,
    const float* __restrict__ bias, float* __restrict__ outp)
{
  __shared__ __bf16 As[3][128 * 32];
  __shared__ __bf16 Bs[3][128 * 32];
  const int tid = threadIdx.x;
  const int lane = tid & 63;
  const int ln = lane & 15, g = lane >> 4;
  const int w = tid >> 6;
  const int wr = w >> 1, wc = w & 1;
  const int id = blockIdx.y * 64 + blockIdx.x;
  const int bx = 8 * (id & 7) + ((id >> 3) & 7);
  const int by = id >> 6;
  const int row0 = bx * 128, col0 = by * 128;

  f32x4 acc[4][4] = {};

  auto stage = [&](int buf, int kt) {
    const int k0 = kt * 32;
#pragma unroll
    for (int i = 0; i < 2; ++i) {
      int c = tid + 256 * i;
      int r = c >> 2, sl = c & 3;
      int so = 8 * (sl ^ ((r >> 1) & 3));
      load_lds16(&A[(size_t)(row0 + r) * 1024 + k0 + so], &As[buf][c * 8]);
      load_lds16(&W[(size_t)(col0 + r) * 1024 + k0 + so], &Bs[buf][c * 8]);
    }
  };

  auto compute = [&](int buf) {
    const __bf16* as = As[buf];
    const __bf16* bs = Bs[buf];
    bf16x8 aF[4], bF[4];
#pragma unroll
    for (int mi = 0; mi < 4; ++mi) {
      int r = wr * 64 + mi * 16 + ln;
      aF[mi] = *(const bf16x8*)&as[r * 32 + ((g * 8) ^ (((r >> 1) & 3) * 8))];
    }
#pragma unroll
    for (int ni = 0; ni < 4; ++ni) {
      int r = wc * 64 + ni * 16 + ln;
      bF[ni] = *(const bf16x8*)&bs[r * 32 + ((g * 8) ^ (((r >> 1) & 3) * 8))];
    }
    __builtin_amdgcn_s_setprio(1);
#pragma unroll
    for (int mi = 0; mi < 4; ++mi)
#pragma unroll
      for (int ni = 0; ni < 4; ++ni)
        acc[mi][ni] = __builtin_amdgcn_mfma_f32_16x16x32_bf16(aF[mi], bF[ni], acc[mi][ni], 0, 0, 0);
    __builtin_amdgcn_s_setprio(0);
  };

  stage(0, 0);
  stage(1, 1);
#pragma unroll 1
  for (int kt = 0; kt < 31; ++kt) {
    asm volatile("s_waitcnt vmcnt(4)" ::: "memory");
    __builtin_amdgcn_s_barrier();
    asm volatile("" ::: "memory");
    if (kt + 2 < 32) stage((kt + 2) % 3, kt + 2);
    compute(kt % 3);
  }
  asm volatile("s_waitcnt vmcnt(0)" ::: "memory");
  __builtin_amdgcn_s_barrier();
  asm volatile("" ::: "memory");
  compute(31 % 3);

#pragma unroll
  for (int ni = 0; ni < 4; ++ni) {
    int n = col0 + wc * 64 + ni * 16 + ln;
    float bv = bias[n];
#pragma unroll
    for (int mi = 0; mi < 4; ++mi) {
#pragma unroll
      for (int i = 0; i < 4; ++i) {
        int m = row0 + wr * 64 + mi * 16 + g * 4 + i;
        outp[(size_t)m * 1024 + n] = acc[mi][ni][i] + bv;
      }
    }
  }
}

// ---------------------------------------------------------------------------
// Causal flash attention (round-14 verified, unchanged): 32x32x16 MFMA,
// swapped-operand, P in registers, exp2-direct softmax (CE pre-folded into
// Qh), permlane32_swap P-redistribution, split-KV 8-wave blocks,
// work-balanced strips.
// ---------------------------------------------------------------------------
__global__ __launch_bounds__(512, 4) void attn_fwd(
    const __bf16* __restrict__ Qh, const __bf16* __restrict__ Kh,
    const __bf16* __restrict__ Vt, __bf16* __restrict__ Ctx)
{
  __shared__ __bf16 KVs[8][64 * 64];                 // 64 KB

  const int tid = threadIdx.x;
  const int lane = tid & 63;
  const int l31 = lane & 31, hl = lane >> 5;
  const int w = tid >> 6;                            // 0..7
  const int wq3 = w & 3, p = w >> 2;                 // q-strip quarter, kv parity
  const int bh = blockIdx.x;
  const int b = bh >> 4, h = bh & 15;

  auto stagePair = [&](int tp) {
    const int base = 2 * (tp & 1);
    const int c = tid;
    const int r = c >> 3, sl = c & 7;
    const int so = 8 * (sl ^ (r & 7));
#pragma unroll
    for (int i = 0; i < 2; ++i) {
      const int kv0 = (2 * tp + i) * 64, s = base + i;
      load_lds16(&Kh[((size_t)bh * 2048 + kv0 + r) * 64 + so], &KVs[s][c * 8]);
      load_lds16(&Vt[((size_t)bh * 64 + r) * 2048 + kv0 + so], &KVs[4 + s][c * 8]);
    }
  };

  auto strip = [&](int qb) {
    const int q0 = qb * 128;
    const int qw = q0 + wq3 * 32;
    const int qglob = qw + l31;
    const int np = qb + 1;

    bf16x8 qF[4];
#pragma unroll
    for (int ds = 0; ds < 4; ++ds)
      qF[ds] = *(const bf16x8*)&Qh[((size_t)bh * 2048 + qglob) * 64 + ds * 16 + hl * 8];

    f32x16 oT[2] = {};
    float lrun = 0.f;

    __syncthreads();
    stagePair(0);
    for (int tp = 0; tp < np; ++tp) {
      __syncthreads();
      if (tp + 1 < np) stagePair(tp + 1);
      const int kv0 = (2 * tp + p) * 64;
      if (kv0 > qw + 31) continue;
      const __bf16* ksm = KVs[2 * (tp & 1) + p];
      const __bf16* vsm = KVs[4 + 2 * (tp & 1) + p];

      f32x16 sT[2] = {};
#pragma unroll
      for (int kblk = 0; kblk < 2; ++kblk) {
        bf16x8 aK[4];
        const int r = kblk * 32 + l31;
#pragma unroll
        for (int ds = 0; ds < 4; ++ds)
          aK[ds] = *(const bf16x8*)&ksm[r * 64 + ((ds * 16 + hl * 8) ^ ((r & 7) * 8))];
        __builtin_amdgcn_s_setprio(1);
#pragma unroll
        for (int ds = 0; ds < 4; ++ds)
          sT[kblk] = __builtin_amdgcn_mfma_f32_32x32x16_bf16(aK[ds], qF[ds], sT[kblk], 0, 0, 0);
        __builtin_amdgcn_s_setprio(0);
      }

      if (kv0 + 63 > qw) {
#pragma unroll
        for (int kblk = 0; kblk < 2; ++kblk)
#pragma unroll
          for (int r = 0; r < 16; ++r) {
            int kvg = kv0 + kblk * 32 + (r & 3) + 8 * (r >> 2) + 4 * hl;
            sT[kblk][r] = (kvg <= qglob) ? sT[kblk][r] : -3e38f;
          }
      }

      unsigned c0[8], c1[8];
      float ps0 = 0.f, ps1 = 0.f, ps2 = 0.f, ps3 = 0.f;
#pragma unroll
      for (int w2 = 0; w2 < 8; ++w2) {
        float p0 = exp2f(sT[0][2 * w2]);
        float p1 = exp2f(sT[0][2 * w2 + 1]);
        float p2 = exp2f(sT[1][2 * w2]);
        float p3 = exp2f(sT[1][2 * w2 + 1]);
        ps0 += p0; ps1 += p1; ps2 += p2; ps3 += p3;
        c0[w2] = cvt_pk_bf16(p0, p1);
        c1[w2] = cvt_pk_bf16(p2, p3);
      }
      lrun += (ps0 + ps1) + (ps2 + ps3);

      // ---- in-register P redistribution via permlane32_swap (T12) ----
      uint32x4 Wv[4];
#pragma unroll
      for (int kblk = 0; kblk < 2; ++kblk)
#pragma unroll
        for (int ksl = 0; ksl < 2; ++ksl)
#pragma unroll
          for (int al = 0; al < 2; ++al) {
            unsigned cp = kblk ? c1[4 * ksl + al]     : c0[4 * ksl + al];
            unsigned cq = kblk ? c1[4 * ksl + 2 + al] : c0[4 * ksl + 2 + al];
            asm volatile("v_permlane32_swap_b32 %0, %1" : "+v"(cp), "+v"(cq));
            Wv[kblk * 2 + ksl][al]     = cp;
            Wv[kblk * 2 + ksl][al + 2] = cq;
          }

#pragma unroll
      for (int dblk = 0; dblk < 2; ++dblk) {
        bf16x8 aV[4];
        const int r = dblk * 32 + l31;
#pragma unroll
        for (int ks = 0; ks < 4; ++ks)
          aV[ks] = *(const bf16x8*)&vsm[r * 64 + ((ks * 16 + hl * 8) ^ ((r & 7) * 8))];
        __builtin_amdgcn_s_setprio(1);
#pragma unroll
        for (int ks = 0; ks < 4; ++ks)
          oT[dblk] = __builtin_amdgcn_mfma_f32_32x32x16_bf16(
              aV[ks], __builtin_bit_cast(bf16x8, Wv[ks]), oT[dblk], 0, 0, 0);
        __builtin_amdgcn_s_setprio(0);
      }
    }

    __syncthreads();
    float* ex = (float*)KVs + wq3 * 2176 + lane * 34;
    if (p == 1) {
      lrun += __shfl_xor(lrun, 32);
#pragma unroll
      for (int dblk = 0; dblk < 2; ++dblk)
#pragma unroll
        for (int rb = 0; rb < 8; ++rb)
          *(float2*)(ex + dblk * 16 + rb * 2) =
              make_float2(oT[dblk][2 * rb], oT[dblk][2 * rb + 1]);
      ex[32] = lrun;
    }
    __syncthreads();
    if (p == 0) {
      lrun += __shfl_xor(lrun, 32);
      lrun += ex[32];
#pragma unroll
      for (int dblk = 0; dblk < 2; ++dblk)
#pragma unroll
        for (int rb = 0; rb < 8; ++rb) {
          float2 v = *(float2*)(ex + dblk * 16 + rb * 2);
          oT[dblk][2 * rb]     += v.x;
          oT[dblk][2 * rb + 1] += v.y;
        }
      const float inv = 1.0f / fmaxf(lrun, 1e-30f);
#pragma unroll
      for (int dblk = 0; dblk < 2; ++dblk)
#pragma unroll
        for (int rb = 0; rb < 4; ++rb) {
          unsigned u0 = cvt_pk_bf16(oT[dblk][4 * rb]     * inv, oT[dblk][4 * rb + 1] * inv);
          unsigned u1 = cvt_pk_bf16(oT[dblk][4 * rb + 2] * inv, oT[dblk][4 * rb + 3] * inv);
          int d = dblk * 32 + rb * 8 + 4 * hl;
          size_t idx = ((size_t)(b * 2048 + qglob)) * 1024 + h * 64 + d;
          *(uint2*)&Ctx[idx] = make_uint2(u0, u1);
        }
    }
  };

  strip(15 - (int)blockIdx.y);
  strip((int)blockIdx.y);
}

// ---------------------------------------------------------------------------
extern "C" void kernel_launch(void* const* d_in, const int* in_sizes, int n_in,
                              void* d_out, int out_size, void* d_ws, size_t ws_size,
                              hipStream_t stream) {
  const float* q  = (const float*)d_in[0];
  const float* k  = (const float*)d_in[1];
  const float* v  = (const float*)d_in[2];
  const float* wq = (const float*)d_in[3];
  const float* bq = (const float*)d_in[4];
  const float* wk = (const float*)d_in[5];
  const float* bk = (const float*)d_in[6];
  const float* wv = (const float*)d_in[7];
  const float* bv = (const float*)d_in[8];
  const float* wo = (const float*)d_in[9];
  const float* bo = (const float*)d_in[10];
  float* out = (float*)d_out;
  char* ws = (char*)d_ws;

  const size_t MB = 1024 * 1024;
  __bf16* Wqb  = (__bf16*)(ws + 0 * MB);
  __bf16* Wkb  = (__bf16*)(ws + 2 * MB);
  __bf16* Wvb  = (__bf16*)(ws + 4 * MB);
  __bf16* Wob  = (__bf16*)(ws + 6 * MB);
  __bf16* Ctx  = (__bf16*)(ws + 8 * MB);   // 16 MB
  __bf16* Qh   = (__bf16*)(ws + 24 * MB);
  __bf16* Kh   = (__bf16*)(ws + 40 * MB);
  __bf16* Vt   = (__bf16*)(ws + 56 * MB);  // ends at 72 MB

  const int W8 = 1024 * 1024 / 8;

  convert_w4<<<2048, 256, 0, stream>>>(wq, wk, wv, wo, Wqb, Wkb, Wvb, Wob, W8);

  gemm_qkv<<<dim3(64, 8, 3), 256, 0, stream>>>(q, k, v, Wqb, Wkb, Wvb,
                                               bq, bk, bv, Qh, Kh, Vt);

  attn_fwd<<<dim3(64, 8), 512, 0, stream>>>(Qh, Kh, Vt, Ctx);

  gemm_out<<<dim3(64, 8), 256, 0, stream>>>(Ctx, Wob, bo, out);
}

// Round 16
// 232.731 us; speedup vs baseline: 3.2406x; 3.2406x over previous
//
#include <hip/hip_runtime.h>

#define DEVI __device__ __forceinline__

typedef __attribute__((ext_vector_type(8))) __bf16 bf16x8;
typedef __attribute__((ext_vector_type(4))) float f32x4;
typedef __attribute__((ext_vector_type(16))) float f32x16;
typedef __attribute__((ext_vector_type(4))) unsigned uint32x4;

DEVI __bf16 f2bf(float f) {
  unsigned u = __builtin_bit_cast(unsigned, f);
  unsigned r = u + 0x7fffu + ((u >> 16) & 1u);
  unsigned short h = (unsigned short)(r >> 16);
  return __builtin_bit_cast(__bf16, h);
}

DEVI unsigned cvt_pk_bf16(float lo, float hi) {
  unsigned r;
  asm("v_cvt_pk_bf16_f32 %0, %1, %2" : "=v"(r) : "v"(lo), "v"(hi));
  return r;
}

DEVI void load_lds16(const void* g, void* l) {
  __builtin_amdgcn_global_load_lds((__attribute__((address_space(1))) const void*)g,
                                   (__attribute__((address_space(3))) void*)l,
                                   16, 0, 0);
}

// all four 1024x1024 weight matrices in one launch
__global__ void convert_w4(const float* __restrict__ w0, const float* __restrict__ w1,
                           const float* __restrict__ w2, const float* __restrict__ w3,
                           __bf16* __restrict__ o0, __bf16* __restrict__ o1,
                           __bf16* __restrict__ o2, __bf16* __restrict__ o3, int n8) {
  int stride = gridDim.x * blockDim.x;
  for (int i = blockIdx.x * blockDim.x + threadIdx.x; i < 4 * n8; i += stride) {
    int sel = i / n8, j = i - sel * n8;
    const float* in = sel == 0 ? w0 : sel == 1 ? w1 : sel == 2 ? w2 : w3;
    __bf16* out = sel == 0 ? o0 : sel == 1 ? o1 : sel == 2 ? o2 : o3;
    float4 a = ((const float4*)in)[j * 2];
    float4 b = ((const float4*)in)[j * 2 + 1];
    bf16x8 o;
    o[0] = f2bf(a.x); o[1] = f2bf(a.y); o[2] = f2bf(a.z); o[3] = f2bf(a.w);
    o[4] = f2bf(b.x); o[5] = f2bf(b.y); o[6] = f2bf(b.z); o[7] = f2bf(b.w);
    ((bf16x8*)out)[j] = o;
  }
}

// ---------------------------------------------------------------------------
// FUSED QKV projection GEMM (round-8/14 proven structure, REVERTED to
// __launch_bounds__(256,3) — round-15's (256,5) forced a 48-VGPR allocator
// budget and spilled the 64-VGPR accumulator to scratch: 1.5GB writes, 4.5x).
// A fp32 -> regs (float4 loads issued after the barrier, latency hides under
// compute) -> cvt_pk -> swizzled ds_write; W via global_load_lds.
// SEL 0: Qh bf16 [BH][S][64], PRE-SCALED by CE. SEL 1: Kh. SEL 2: Vt [BH][64][S].
// ---------------------------------------------------------------------------
__global__ __launch_bounds__(256, 3) void gemm_qkv(
    const float* __restrict__ qa, const float* __restrict__ ka, const float* __restrict__ va,
    const __bf16* __restrict__ Wq, const __bf16* __restrict__ Wk, const __bf16* __restrict__ Wv,
    const float* __restrict__ bq, const float* __restrict__ bk, const float* __restrict__ bv,
    __bf16* __restrict__ Qh, __bf16* __restrict__ Kh, __bf16* __restrict__ Vt)
{
  __shared__ __align__(16) __bf16 As[2][128 * 32];
  __shared__ __align__(16) __bf16 Bs[2][128 * 32];
  const int sel = blockIdx.z;
  const float* A = sel == 0 ? qa : sel == 1 ? ka : va;
  const __bf16* W = sel == 0 ? Wq : sel == 1 ? Wk : Wv;
  const float* bias = sel == 0 ? bq : sel == 1 ? bk : bv;
  __bf16* outp = sel == 0 ? Qh : sel == 1 ? Kh : Vt;
  const bool vmode = (sel == 2);
  const float osc = (sel == 0) ? 0.18033688f : 1.0f; // CE = (1/8)*log2(e) into Q

  const int tid = threadIdx.x;
  const int lane = tid & 63;
  const int ln = lane & 15, g = lane >> 4;
  const int w = tid >> 6;
  const int wr = w >> 1, wc = w & 1;
  const int id = blockIdx.y * 64 + blockIdx.x;
  const int bx = 8 * (id & 7) + ((id >> 3) & 7);     // XCD swizzle
  const int by = id >> 6;
  const int row0 = bx * 128, col0 = by * 128;

  const int ar = tid >> 1, ah = tid & 1;   // A staging: row (0..127), half (16 floats)
  const int axr = (ar >> 1) & 3;           // row swizzle term

  f32x4 acc[4][4] = {};
  float4 fA[4];

  auto issueA = [&](int kt) {              // 64B fp32 per thread -> regs
    const float4* src = (const float4*)&A[(size_t)(row0 + ar) * 1024 + kt * 32 + ah * 16];
#pragma unroll
    for (int j = 0; j < 4; ++j) fA[j] = src[j];
  };
  auto issueW = [&](int buf, int kt) {     // 2x gload_lds per thread
#pragma unroll
    for (int i = 0; i < 2; ++i) {
      int c = tid + 256 * i;
      int r = c >> 2, sl = c & 3;
      int so = 8 * (sl ^ ((r >> 1) & 3));  // inverse-swizzled source slot
      load_lds16(&W[(size_t)(col0 + r) * 1024 + kt * 32 + so], &Bs[buf][c * 8]);
    }
  };
  auto writeA = [&](int buf) {             // cvt + swizzled ds_write_b128 x2
#pragma unroll
    for (int j = 0; j < 2; ++j) {
      uint32x4 o;
      o[0] = cvt_pk_bf16(fA[2 * j].x, fA[2 * j].y);
      o[1] = cvt_pk_bf16(fA[2 * j].z, fA[2 * j].w);
      o[2] = cvt_pk_bf16(fA[2 * j + 1].x, fA[2 * j + 1].y);
      o[3] = cvt_pk_bf16(fA[2 * j + 1].z, fA[2 * j + 1].w);
      int s = 2 * ah + j;                  // source 16B slot
      *(uint32x4*)&As[buf][ar * 32 + (s ^ axr) * 8] = o;   // LDS slot = s ^ x
    }
  };
  auto compute = [&](int buf) {
    const __bf16* as = As[buf];
    const __bf16* bs = Bs[buf];
    bf16x8 aF[4], bF[4];
#pragma unroll
    for (int mi = 0; mi < 4; ++mi) {
      int r = wr * 64 + mi * 16 + ln;
      aF[mi] = *(const bf16x8*)&as[r * 32 + ((g * 8) ^ (((r >> 1) & 3) * 8))];
    }
#pragma unroll
    for (int ni = 0; ni < 4; ++ni) {
      int r = wc * 64 + ni * 16 + ln;
      bF[ni] = *(const bf16x8*)&bs[r * 32 + ((g * 8) ^ (((r >> 1) & 3) * 8))];
    }
    __builtin_amdgcn_s_setprio(1);
#pragma unroll
    for (int mi = 0; mi < 4; ++mi)
#pragma unroll
      for (int ni = 0; ni < 4; ++ni)
        acc[mi][ni] = __builtin_amdgcn_mfma_f32_16x16x32_bf16(aF[mi], bF[ni], acc[mi][ni], 0, 0, 0);
    __builtin_amdgcn_s_setprio(0);
  };

  // prologue: stage tile 0
  issueA(0); issueW(0, 0);
  writeA(0);                               // compiler waits for fA loads
  __syncthreads();                         // drains W(0) gload_lds, publishes buf0
#pragma unroll 1
  for (int kt = 0; kt < 32; ++kt) {
    const int cur = kt & 1, nxt = cur ^ 1;
    if (kt + 1 < 32) { issueA(kt + 1); issueW(nxt, kt + 1); }   // latency under compute
    compute(cur);
    if (kt + 1 < 32) writeA(nxt);          // regs -> LDS (other buffer)
    __syncthreads();                       // drain + publish buf nxt
  }

#pragma unroll
  for (int ni = 0; ni < 4; ++ni) {
    int n = col0 + wc * 64 + ni * 16 + ln;
    float bv = bias[n];
#pragma unroll
    for (int mi = 0; mi < 4; ++mi) {
#pragma unroll
      for (int i = 0; i < 4; ++i) {
        int m = row0 + wr * 64 + mi * 16 + g * 4 + i;   // C-layout: row=(l>>4)*4+i, col=l&15
        float val = (acc[mi][ni][i] + bv) * osc;
        int b = m >> 11, s = m & 2047, h = n >> 6, d = n & 63;
        size_t idx = vmode
          ? ((size_t)((b * 16 + h) * 64 + d) * 2048 + s)
          : ((size_t)((b * 16 + h) * 2048 + s) * 64 + d);
        outp[idx] = f2bf(val);
      }
    }
  }
}

// ---------------------------------------------------------------------------
// Output GEMM (bf16 A = Ctx): depth-2 counted-vmcnt, fp32 out (proven 20us,
// REVERTED to __launch_bounds__(256,2)).
// ---------------------------------------------------------------------------
__global__ __launch_bounds__(256, 2) void gemm_out(
    const __bf16* __restrict__ A, const __bf16* __restrict__ W,
    const float* __restrict__ bias, float* __restrict__ outp)
{
  __shared__ __bf16 As[3][128 * 32];
  __shared__ __bf16 Bs[3][128 * 32];
  const int tid = threadIdx.x;
  const int lane = tid & 63;
  const int ln = lane & 15, g = lane >> 4;
  const int w = tid >> 6;
  const int wr = w >> 1, wc = w & 1;
  const int id = blockIdx.y * 64 + blockIdx.x;
  const int bx = 8 * (id & 7) + ((id >> 3) & 7);
  const int by = id >> 6;
  const int row0 = bx * 128, col0 = by * 128;

  f32x4 acc[4][4] = {};

  auto stage = [&](int buf, int kt) {
    const int k0 = kt * 32;
#pragma unroll
    for (int i = 0; i < 2; ++i) {
      int c = tid + 256 * i;
      int r = c >> 2, sl = c & 3;
      int so = 8 * (sl ^ ((r >> 1) & 3));
      load_lds16(&A[(size_t)(row0 + r) * 1024 + k0 + so], &As[buf][c * 8]);
      load_lds16(&W[(size_t)(col0 + r) * 1024 + k0 + so], &Bs[buf][c * 8]);
    }
  };

  auto compute = [&](int buf) {
    const __bf16* as = As[buf];
    const __bf16* bs = Bs[buf];
    bf16x8 aF[4], bF[4];
#pragma unroll
    for (int mi = 0; mi < 4; ++mi) {
      int r = wr * 64 + mi * 16 + ln;
      aF[mi] = *(const bf16x8*)&as[r * 32 + ((g * 8) ^ (((r >> 1) & 3) * 8))];
    }
#pragma unroll
    for (int ni = 0; ni < 4; ++ni) {
      int r = wc * 64 + ni * 16 + ln;
      bF[ni] = *(const bf16x8*)&bs[r * 32 + ((g * 8) ^ (((r >> 1) & 3) * 8))];
    }
    __builtin_amdgcn_s_setprio(1);
#pragma unroll
    for (int mi = 0; mi < 4; ++mi)
#pragma unroll
      for (int ni = 0; ni < 4; ++ni)
        acc[mi][ni] = __builtin_amdgcn_mfma_f32_16x16x32_bf16(aF[mi], bF[ni], acc[mi][ni], 0, 0, 0);
    __builtin_amdgcn_s_setprio(0);
  };

  stage(0, 0);
  stage(1, 1);
#pragma unroll 1
  for (int kt = 0; kt < 31; ++kt) {
    asm volatile("s_waitcnt vmcnt(4)" ::: "memory");
    __builtin_amdgcn_s_barrier();
    asm volatile("" ::: "memory");
    if (kt + 2 < 32) stage((kt + 2) % 3, kt + 2);
    compute(kt % 3);
  }
  asm volatile("s_waitcnt vmcnt(0)" ::: "memory");
  __builtin_amdgcn_s_barrier();
  asm volatile("" ::: "memory");
  compute(31 % 3);

#pragma unroll
  for (int ni = 0; ni < 4; ++ni) {
    int n = col0 + wc * 64 + ni * 16 + ln;
    float bv = bias[n];
#pragma unroll
    for (int mi = 0; mi < 4; ++mi) {
#pragma unroll
      for (int i = 0; i < 4; ++i) {
        int m = row0 + wr * 64 + mi * 16 + g * 4 + i;
        outp[(size_t)m * 1024 + n] = acc[mi][ni][i] + bv;
      }
    }
  }
}

// ---------------------------------------------------------------------------
// Causal flash attention (round-14 verified structure). NEW this round:
// softmax denominator l computed on the MFMA pipe — oL = mfma(ones, Wv[ks],
// oL): with A=all-ones, D[m][q] = sum_k B[k][q] (layout-independent), so any
// oL row holds sum_kv P[kv][q] for this wave's tiles. Deletes 32 VALU adds
// per tile-step + the cross-half shfl (MFMA sums the full k span); exp2
// results now feed only cvt_pk. l sums the same bf16-rounded P used in PV.
// ---------------------------------------------------------------------------
__global__ __launch_bounds__(512, 4) void attn_fwd(
    const __bf16* __restrict__ Qh, const __bf16* __restrict__ Kh,
    const __bf16* __restrict__ Vt, __bf16* __restrict__ Ctx)
{
  __shared__ __bf16 KVs[8][64 * 64];                 // 64 KB

  const int tid = threadIdx.x;
  const int lane = tid & 63;
  const int l31 = lane & 31, hl = lane >> 5;
  const int w = tid >> 6;                            // 0..7
  const int wq3 = w & 3, p = w >> 2;                 // q-strip quarter, kv parity
  const int bh = blockIdx.x;
  const int b = bh >> 4, h = bh & 15;

  const uint32x4 onesw = {0x3F803F80u, 0x3F803F80u, 0x3F803F80u, 0x3F803F80u};
  const bf16x8 onesA = __builtin_bit_cast(bf16x8, onesw);   // bf16 1.0 x8

  auto stagePair = [&](int tp) {
    const int base = 2 * (tp & 1);
    const int c = tid;
    const int r = c >> 3, sl = c & 7;
    const int so = 8 * (sl ^ (r & 7));
#pragma unroll
    for (int i = 0; i < 2; ++i) {
      const int kv0 = (2 * tp + i) * 64, s = base + i;
      load_lds16(&Kh[((size_t)bh * 2048 + kv0 + r) * 64 + so], &KVs[s][c * 8]);
      load_lds16(&Vt[((size_t)bh * 64 + r) * 2048 + kv0 + so], &KVs[4 + s][c * 8]);
    }
  };

  auto strip = [&](int qb) {
    const int q0 = qb * 128;
    const int qw = q0 + wq3 * 32;
    const int qglob = qw + l31;
    const int np = qb + 1;

    bf16x8 qF[4];
#pragma unroll
    for (int ds = 0; ds < 4; ++ds)
      qF[ds] = *(const bf16x8*)&Qh[((size_t)bh * 2048 + qglob) * 64 + ds * 16 + hl * 8];

    f32x16 oT[2] = {};
    f32x16 oL = {};                                  // l accumulator (MFMA path)

    __syncthreads();
    stagePair(0);
    for (int tp = 0; tp < np; ++tp) {
      __syncthreads();
      if (tp + 1 < np) stagePair(tp + 1);
      const int kv0 = (2 * tp + p) * 64;
      if (kv0 > qw + 31) continue;
      const __bf16* ksm = KVs[2 * (tp & 1) + p];
      const __bf16* vsm = KVs[4 + 2 * (tp & 1) + p];

      f32x16 sT[2] = {};
#pragma unroll
      for (int kblk = 0; kblk < 2; ++kblk) {
        bf16x8 aK[4];
        const int r = kblk * 32 + l31;
#pragma unroll
        for (int ds = 0; ds < 4; ++ds)
          aK[ds] = *(const bf16x8*)&ksm[r * 64 + ((ds * 16 + hl * 8) ^ ((r & 7) * 8))];
        __builtin_amdgcn_s_setprio(1);
#pragma unroll
        for (int ds = 0; ds < 4; ++ds)
          sT[kblk] = __builtin_amdgcn_mfma_f32_32x32x16_bf16(aK[ds], qF[ds], sT[kblk], 0, 0, 0);
        __builtin_amdgcn_s_setprio(0);
      }

      if (kv0 + 63 > qw) {
#pragma unroll
        for (int kblk = 0; kblk < 2; ++kblk)
#pragma unroll
          for (int r = 0; r < 16; ++r) {
            int kvg = kv0 + kblk * 32 + (r & 3) + 8 * (r >> 2) + 4 * hl;
            sT[kblk][r] = (kvg <= qglob) ? sT[kblk][r] : -3e38f;
          }
      }

      unsigned c0[8], c1[8];
#pragma unroll
      for (int w2 = 0; w2 < 8; ++w2) {
        float p0 = exp2f(sT[0][2 * w2]);
        float p1 = exp2f(sT[0][2 * w2 + 1]);
        float p2 = exp2f(sT[1][2 * w2]);
        float p3 = exp2f(sT[1][2 * w2 + 1]);
        c0[w2] = cvt_pk_bf16(p0, p1);
        c1[w2] = cvt_pk_bf16(p2, p3);
      }

      // ---- in-register P redistribution via permlane32_swap (T12) ----
      uint32x4 Wv[4];
#pragma unroll
      for (int kblk = 0; kblk < 2; ++kblk)
#pragma unroll
        for (int ksl = 0; ksl < 2; ++ksl)
#pragma unroll
          for (int al = 0; al < 2; ++al) {
            unsigned cp = kblk ? c1[4 * ksl + al]     : c0[4 * ksl + al];
            unsigned cq = kblk ? c1[4 * ksl + 2 + al] : c0[4 * ksl + 2 + al];
            asm volatile("v_permlane32_swap_b32 %0, %1" : "+v"(cp), "+v"(cq));
            Wv[kblk * 2 + ksl][al]     = cp;
            Wv[kblk * 2 + ksl][al + 2] = cq;
          }

      // ---- l += sum_kv P : ones-MFMA (every row of oL = column sum) ----
      __builtin_amdgcn_s_setprio(1);
#pragma unroll
      for (int ks = 0; ks < 4; ++ks)
        oL = __builtin_amdgcn_mfma_f32_32x32x16_bf16(
            onesA, __builtin_bit_cast(bf16x8, Wv[ks]), oL, 0, 0, 0);
      __builtin_amdgcn_s_setprio(0);

#pragma unroll
      for (int dblk = 0; dblk < 2; ++dblk) {
        bf16x8 aV[4];
        const int r = dblk * 32 + l31;
#pragma unroll
        for (int ks = 0; ks < 4; ++ks)
          aV[ks] = *(const bf16x8*)&vsm[r * 64 + ((ks * 16 + hl * 8) ^ ((r & 7) * 8))];
        __builtin_amdgcn_s_setprio(1);
#pragma unroll
        for (int ks = 0; ks < 4; ++ks)
          oT[dblk] = __builtin_amdgcn_mfma_f32_32x32x16_bf16(
              aV[ks], __builtin_bit_cast(bf16x8, Wv[ks]), oT[dblk], 0, 0, 0);
        __builtin_amdgcn_s_setprio(0);
      }
    }

    float lrun = oL[0];                              // all rows equal; full k-span
    __syncthreads();
    float* ex = (float*)KVs + wq3 * 2176 + lane * 34;
    if (p == 1) {
#pragma unroll
      for (int dblk = 0; dblk < 2; ++dblk)
#pragma unroll
        for (int rb = 0; rb < 8; ++rb)
          *(float2*)(ex + dblk * 16 + rb * 2) =
              make_float2(oT[dblk][2 * rb], oT[dblk][2 * rb + 1]);
      ex[32] = lrun;
    }
    __syncthreads();
    if (p == 0) {
      lrun += ex[32];
#pragma unroll
      for (int dblk = 0; dblk < 2; ++dblk)
#pragma unroll
        for (int rb = 0; rb < 8; ++rb) {
          float2 v = *(float2*)(ex + dblk * 16 + rb * 2);
          oT[dblk][2 * rb]     += v.x;
          oT[dblk][2 * rb + 1] += v.y;
        }
      const float inv = 1.0f / fmaxf(lrun, 1e-30f);
#pragma unroll
      for (int dblk = 0; dblk < 2; ++dblk)
#pragma unroll
        for (int rb = 0; rb < 4; ++rb) {
          unsigned u0 = cvt_pk_bf16(oT[dblk][4 * rb]     * inv, oT[dblk][4 * rb + 1] * inv);
          unsigned u1 = cvt_pk_bf16(oT[dblk][4 * rb + 2] * inv, oT[dblk][4 * rb + 3] * inv);
          int d = dblk * 32 + rb * 8 + 4 * hl;
          size_t idx = ((size_t)(b * 2048 + qglob)) * 1024 + h * 64 + d;
          *(uint2*)&Ctx[idx] = make_uint2(u0, u1);
        }
    }
  };

  strip(15 - (int)blockIdx.y);
  strip((int)blockIdx.y);
}

// ---------------------------------------------------------------------------
extern "C" void kernel_launch(void* const* d_in, const int* in_sizes, int n_in,
                              void* d_out, int out_size, void* d_ws, size_t ws_size,
                              hipStream_t stream) {
  const float* q  = (const float*)d_in[0];
  const float* k  = (const float*)d_in[1];
  const float* v  = (const float*)d_in[2];
  const float* wq = (const float*)d_in[3];
  const float* bq = (const float*)d_in[4];
  const float* wk = (const float*)d_in[5];
  const float* bk = (const float*)d_in[6];
  const float* wv = (const float*)d_in[7];
  const float* bv = (const float*)d_in[8];
  const float* wo = (const float*)d_in[9];
  const float* bo = (const float*)d_in[10];
  float* out = (float*)d_out;
  char* ws = (char*)d_ws;

  const size_t MB = 1024 * 1024;
  __bf16* Wqb  = (__bf16*)(ws + 0 * MB);
  __bf16* Wkb  = (__bf16*)(ws + 2 * MB);
  __bf16* Wvb  = (__bf16*)(ws + 4 * MB);
  __bf16* Wob  = (__bf16*)(ws + 6 * MB);
  __bf16* Ctx  = (__bf16*)(ws + 8 * MB);   // 16 MB
  __bf16* Qh   = (__bf16*)(ws + 24 * MB);
  __bf16* Kh   = (__bf16*)(ws + 40 * MB);
  __bf16* Vt   = (__bf16*)(ws + 56 * MB);  // ends at 72 MB

  const int W8 = 1024 * 1024 / 8;

  convert_w4<<<2048, 256, 0, stream>>>(wq, wk, wv, wo, Wqb, Wkb, Wvb, Wob, W8);

  gemm_qkv<<<dim3(64, 8, 3), 256, 0, stream>>>(q, k, v, Wqb, Wkb, Wvb,
                                               bq, bk, bv, Qh, Kh, Vt);

  attn_fwd<<<dim3(64, 8), 512, 0, stream>>>(Qh, Kh, Vt, Ctx);

  gemm_out<<<dim3(64, 8), 256, 0, stream>>>(Ctx, Wob, bo, out);
}

// Round 17
// 197.608 us; speedup vs baseline: 3.8166x; 1.1777x over previous
//
#include <hip/hip_runtime.h>

#define DEVI __device__ __forceinline__

typedef __attribute__((ext_vector_type(8))) __bf16 bf16x8;
typedef __attribute__((ext_vector_type(4))) float f32x4;
typedef __attribute__((ext_vector_type(16))) float f32x16;
typedef __attribute__((ext_vector_type(4))) unsigned uint32x4;

DEVI __bf16 f2bf(float f) {
  unsigned u = __builtin_bit_cast(unsigned, f);
  unsigned r = u + 0x7fffu + ((u >> 16) & 1u);
  unsigned short h = (unsigned short)(r >> 16);
  return __builtin_bit_cast(__bf16, h);
}

DEVI unsigned cvt_pk_bf16(float lo, float hi) {
  unsigned r;
  asm("v_cvt_pk_bf16_f32 %0, %1, %2" : "=v"(r) : "v"(lo), "v"(hi));
  return r;
}

DEVI void load_lds16(const void* g, void* l) {
  __builtin_amdgcn_global_load_lds((__attribute__((address_space(1))) const void*)g,
                                   (__attribute__((address_space(3))) void*)l,
                                   16, 0, 0);
}

// all four 1024x1024 weight matrices in one launch
__global__ void convert_w4(const float* __restrict__ w0, const float* __restrict__ w1,
                           const float* __restrict__ w2, const float* __restrict__ w3,
                           __bf16* __restrict__ o0, __bf16* __restrict__ o1,
                           __bf16* __restrict__ o2, __bf16* __restrict__ o3, int n8) {
  int stride = gridDim.x * blockDim.x;
  for (int i = blockIdx.x * blockDim.x + threadIdx.x; i < 4 * n8; i += stride) {
    int sel = i / n8, j = i - sel * n8;
    const float* in = sel == 0 ? w0 : sel == 1 ? w1 : sel == 2 ? w2 : w3;
    __bf16* out = sel == 0 ? o0 : sel == 1 ? o1 : sel == 2 ? o2 : o3;
    float4 a = ((const float4*)in)[j * 2];
    float4 b = ((const float4*)in)[j * 2 + 1];
    bf16x8 o;
    o[0] = f2bf(a.x); o[1] = f2bf(a.y); o[2] = f2bf(a.z); o[3] = f2bf(a.w);
    o[4] = f2bf(b.x); o[5] = f2bf(b.y); o[6] = f2bf(b.z); o[7] = f2bf(b.w);
    ((bf16x8*)out)[j] = o;
  }
}

// ---------------------------------------------------------------------------
// FUSED QKV projection GEMM (round-8/14 proven structure). ONLY CHANGE:
// __launch_bounds__(256,3) -> (256,4). Allocator budget 512/4 = 128 VGPR >=
// the 68 this kernel uses (no spill possible, unlike round-15's (256,5)
// whose 102-budget collapsed to 48 and spilled the accumulator); LDS 4x32KB
// = 128 <= 160. If the bound drives residency: 16 waves/CU on a latency-
// bound kernel (MfmaUtil 13.5 / VALUBusy 11.8); else exact no-op.
// A fp32 -> regs (float4 loads issued after the barrier, latency hides under
// compute) -> cvt_pk -> swizzled ds_write; W via global_load_lds.
// SEL 0: Qh bf16 [BH][S][64], PRE-SCALED by CE. SEL 1: Kh. SEL 2: Vt [BH][64][S].
// ---------------------------------------------------------------------------
__global__ __launch_bounds__(256, 4) void gemm_qkv(
    const float* __restrict__ qa, const float* __restrict__ ka, const float* __restrict__ va,
    const __bf16* __restrict__ Wq, const __bf16* __restrict__ Wk, const __bf16* __restrict__ Wv,
    const float* __restrict__ bq, const float* __restrict__ bk, const float* __restrict__ bv,
    __bf16* __restrict__ Qh, __bf16* __restrict__ Kh, __bf16* __restrict__ Vt)
{
  __shared__ __align__(16) __bf16 As[2][128 * 32];
  __shared__ __align__(16) __bf16 Bs[2][128 * 32];
  const int sel = blockIdx.z;
  const float* A = sel == 0 ? qa : sel == 1 ? ka : va;
  const __bf16* W = sel == 0 ? Wq : sel == 1 ? Wk : Wv;
  const float* bias = sel == 0 ? bq : sel == 1 ? bk : bv;
  __bf16* outp = sel == 0 ? Qh : sel == 1 ? Kh : Vt;
  const bool vmode = (sel == 2);
  const float osc = (sel == 0) ? 0.18033688f : 1.0f; // CE = (1/8)*log2(e) into Q

  const int tid = threadIdx.x;
  const int lane = tid & 63;
  const int ln = lane & 15, g = lane >> 4;
  const int w = tid >> 6;
  const int wr = w >> 1, wc = w & 1;
  const int id = blockIdx.y * 64 + blockIdx.x;
  const int bx = 8 * (id & 7) + ((id >> 3) & 7);     // XCD swizzle
  const int by = id >> 6;
  const int row0 = bx * 128, col0 = by * 128;

  const int ar = tid >> 1, ah = tid & 1;   // A staging: row (0..127), half (16 floats)
  const int axr = (ar >> 1) & 3;           // row swizzle term

  f32x4 acc[4][4] = {};
  float4 fA[4];

  auto issueA = [&](int kt) {              // 64B fp32 per thread -> regs
    const float4* src = (const float4*)&A[(size_t)(row0 + ar) * 1024 + kt * 32 + ah * 16];
#pragma unroll
    for (int j = 0; j < 4; ++j) fA[j] = src[j];
  };
  auto issueW = [&](int buf, int kt) {     // 2x gload_lds per thread
#pragma unroll
    for (int i = 0; i < 2; ++i) {
      int c = tid + 256 * i;
      int r = c >> 2, sl = c & 3;
      int so = 8 * (sl ^ ((r >> 1) & 3));  // inverse-swizzled source slot
      load_lds16(&W[(size_t)(col0 + r) * 1024 + kt * 32 + so], &Bs[buf][c * 8]);
    }
  };
  auto writeA = [&](int buf) {             // cvt + swizzled ds_write_b128 x2
#pragma unroll
    for (int j = 0; j < 2; ++j) {
      uint32x4 o;
      o[0] = cvt_pk_bf16(fA[2 * j].x, fA[2 * j].y);
      o[1] = cvt_pk_bf16(fA[2 * j].z, fA[2 * j].w);
      o[2] = cvt_pk_bf16(fA[2 * j + 1].x, fA[2 * j + 1].y);
      o[3] = cvt_pk_bf16(fA[2 * j + 1].z, fA[2 * j + 1].w);
      int s = 2 * ah + j;                  // source 16B slot
      *(uint32x4*)&As[buf][ar * 32 + (s ^ axr) * 8] = o;   // LDS slot = s ^ x
    }
  };
  auto compute = [&](int buf) {
    const __bf16* as = As[buf];
    const __bf16* bs = Bs[buf];
    bf16x8 aF[4], bF[4];
#pragma unroll
    for (int mi = 0; mi < 4; ++mi) {
      int r = wr * 64 + mi * 16 + ln;
      aF[mi] = *(const bf16x8*)&as[r * 32 + ((g * 8) ^ (((r >> 1) & 3) * 8))];
    }
#pragma unroll
    for (int ni = 0; ni < 4; ++ni) {
      int r = wc * 64 + ni * 16 + ln;
      bF[ni] = *(const bf16x8*)&bs[r * 32 + ((g * 8) ^ (((r >> 1) & 3) * 8))];
    }
    __builtin_amdgcn_s_setprio(1);
#pragma unroll
    for (int mi = 0; mi < 4; ++mi)
#pragma unroll
      for (int ni = 0; ni < 4; ++ni)
        acc[mi][ni] = __builtin_amdgcn_mfma_f32_16x16x32_bf16(aF[mi], bF[ni], acc[mi][ni], 0, 0, 0);
    __builtin_amdgcn_s_setprio(0);
  };

  // prologue: stage tile 0
  issueA(0); issueW(0, 0);
  writeA(0);                               // compiler waits for fA loads
  __syncthreads();                         // drains W(0) gload_lds, publishes buf0
#pragma unroll 1
  for (int kt = 0; kt < 32; ++kt) {
    const int cur = kt & 1, nxt = cur ^ 1;
    if (kt + 1 < 32) { issueA(kt + 1); issueW(nxt, kt + 1); }   // latency under compute
    compute(cur);
    if (kt + 1 < 32) writeA(nxt);          // regs -> LDS (other buffer)
    __syncthreads();                       // drain + publish buf nxt
  }

#pragma unroll
  for (int ni = 0; ni < 4; ++ni) {
    int n = col0 + wc * 64 + ni * 16 + ln;
    float bv = bias[n];
#pragma unroll
    for (int mi = 0; mi < 4; ++mi) {
#pragma unroll
      for (int i = 0; i < 4; ++i) {
        int m = row0 + wr * 64 + mi * 16 + g * 4 + i;   // C-layout: row=(l>>4)*4+i, col=l&15
        float val = (acc[mi][ni][i] + bv) * osc;
        int b = m >> 11, s = m & 2047, h = n >> 6, d = n & 63;
        size_t idx = vmode
          ? ((size_t)((b * 16 + h) * 64 + d) * 2048 + s)
          : ((size_t)((b * 16 + h) * 2048 + s) * 64 + d);
        outp[idx] = f2bf(val);
      }
    }
  }
}

// ---------------------------------------------------------------------------
// Output GEMM (bf16 A = Ctx): depth-2 counted-vmcnt, fp32 out (proven 20us).
// ---------------------------------------------------------------------------
__global__ __launch_bounds__(256, 2) void gemm_out(
    const __bf16* __restrict__ A, const __bf16* __restrict__ W,
    const float* __restrict__ bias, float* __restrict__ outp)
{
  __shared__ __bf16 As[3][128 * 32];
  __shared__ __bf16 Bs[3][128 * 32];
  const int tid = threadIdx.x;
  const int lane = tid & 63;
  const int ln = lane & 15, g = lane >> 4;
  const int w = tid >> 6;
  const int wr = w >> 1, wc = w & 1;
  const int id = blockIdx.y * 64 + blockIdx.x;
  const int bx = 8 * (id & 7) + ((id >> 3) & 7);
  const int by = id >> 6;
  const int row0 = bx * 128, col0 = by * 128;

  f32x4 acc[4][4] = {};

  auto stage = [&](int buf, int kt) {
    const int k0 = kt * 32;
#pragma unroll
    for (int i = 0; i < 2; ++i) {
      int c = tid + 256 * i;
      int r = c >> 2, sl = c & 3;
      int so = 8 * (sl ^ ((r >> 1) & 3));
      load_lds16(&A[(size_t)(row0 + r) * 1024 + k0 + so], &As[buf][c * 8]);
      load_lds16(&W[(size_t)(col0 + r) * 1024 + k0 + so], &Bs[buf][c * 8]);
    }
  };

  auto compute = [&](int buf) {
    const __bf16* as = As[buf];
    const __bf16* bs = Bs[buf];
    bf16x8 aF[4], bF[4];
#pragma unroll
    for (int mi = 0; mi < 4; ++mi) {
      int r = wr * 64 + mi * 16 + ln;
      aF[mi] = *(const bf16x8*)&as[r * 32 + ((g * 8) ^ (((r >> 1) & 3) * 8))];
    }
#pragma unroll
    for (int ni = 0; ni < 4; ++ni) {
      int r = wc * 64 + ni * 16 + ln;
      bF[ni] = *(const bf16x8*)&bs[r * 32 + ((g * 8) ^ (((r >> 1) & 3) * 8))];
    }
    __builtin_amdgcn_s_setprio(1);
#pragma unroll
    for (int mi = 0; mi < 4; ++mi)
#pragma unroll
      for (int ni = 0; ni < 4; ++ni)
        acc[mi][ni] = __builtin_amdgcn_mfma_f32_16x16x32_bf16(aF[mi], bF[ni], acc[mi][ni], 0, 0, 0);
    __builtin_amdgcn_s_setprio(0);
  };

  stage(0, 0);
  stage(1, 1);
#pragma unroll 1
  for (int kt = 0; kt < 31; ++kt) {
    asm volatile("s_waitcnt vmcnt(4)" ::: "memory");
    __builtin_amdgcn_s_barrier();
    asm volatile("" ::: "memory");
    if (kt + 2 < 32) stage((kt + 2) % 3, kt + 2);
    compute(kt % 3);
  }
  asm volatile("s_waitcnt vmcnt(0)" ::: "memory");
  __builtin_amdgcn_s_barrier();
  asm volatile("" ::: "memory");
  compute(31 % 3);

#pragma unroll
  for (int ni = 0; ni < 4; ++ni) {
    int n = col0 + wc * 64 + ni * 16 + ln;
    float bv = bias[n];
#pragma unroll
    for (int mi = 0; mi < 4; ++mi) {
#pragma unroll
      for (int i = 0; i < 4; ++i) {
        int m = row0 + wr * 64 + mi * 16 + g * 4 + i;
        outp[(size_t)m * 1024 + n] = acc[mi][ni][i] + bv;
      }
    }
  }
}

// ---------------------------------------------------------------------------
// Causal flash attention — REVERTED to the round-14 verified version (the
// 202.75us best): 32x32x16 MFMA, swapped-operand, P in registers,
// exp2-direct softmax (CE pre-folded into Qh), permlane32_swap
// P-redistribution, VALU lrun accumulation (round-16's ones-MFMA l created a
// loop-carried serial MFMA chain: attn 76 -> ~106us; reverted).
// ---------------------------------------------------------------------------
__global__ __launch_bounds__(512, 4) void attn_fwd(
    const __bf16* __restrict__ Qh, const __bf16* __restrict__ Kh,
    const __bf16* __restrict__ Vt, __bf16* __restrict__ Ctx)
{
  __shared__ __bf16 KVs[8][64 * 64];                 // 64 KB

  const int tid = threadIdx.x;
  const int lane = tid & 63;
  const int l31 = lane & 31, hl = lane >> 5;
  const int w = tid >> 6;                            // 0..7
  const int wq3 = w & 3, p = w >> 2;                 // q-strip quarter, kv parity
  const int bh = blockIdx.x;
  const int b = bh >> 4, h = bh & 15;

  auto stagePair = [&](int tp) {
    const int base = 2 * (tp & 1);
    const int c = tid;
    const int r = c >> 3, sl = c & 7;
    const int so = 8 * (sl ^ (r & 7));
#pragma unroll
    for (int i = 0; i < 2; ++i) {
      const int kv0 = (2 * tp + i) * 64, s = base + i;
      load_lds16(&Kh[((size_t)bh * 2048 + kv0 + r) * 64 + so], &KVs[s][c * 8]);
      load_lds16(&Vt[((size_t)bh * 64 + r) * 2048 + kv0 + so], &KVs[4 + s][c * 8]);
    }
  };

  auto strip = [&](int qb) {
    const int q0 = qb * 128;
    const int qw = q0 + wq3 * 32;
    const int qglob = qw + l31;
    const int np = qb + 1;

    bf16x8 qF[4];
#pragma unroll
    for (int ds = 0; ds < 4; ++ds)
      qF[ds] = *(const bf16x8*)&Qh[((size_t)bh * 2048 + qglob) * 64 + ds * 16 + hl * 8];

    f32x16 oT[2] = {};
    float lrun = 0.f;

    __syncthreads();
    stagePair(0);
    for (int tp = 0; tp < np; ++tp) {
      __syncthreads();
      if (tp + 1 < np) stagePair(tp + 1);
      const int kv0 = (2 * tp + p) * 64;
      if (kv0 > qw + 31) continue;
      const __bf16* ksm = KVs[2 * (tp & 1) + p];
      const __bf16* vsm = KVs[4 + 2 * (tp & 1) + p];

      f32x16 sT[2] = {};
#pragma unroll
      for (int kblk = 0; kblk < 2; ++kblk) {
        bf16x8 aK[4];
        const int r = kblk * 32 + l31;
#pragma unroll
        for (int ds = 0; ds < 4; ++ds)
          aK[ds] = *(const bf16x8*)&ksm[r * 64 + ((ds * 16 + hl * 8) ^ ((r & 7) * 8))];
        __builtin_amdgcn_s_setprio(1);
#pragma unroll
        for (int ds = 0; ds < 4; ++ds)
          sT[kblk] = __builtin_amdgcn_mfma_f32_32x32x16_bf16(aK[ds], qF[ds], sT[kblk], 0, 0, 0);
        __builtin_amdgcn_s_setprio(0);
      }

      if (kv0 + 63 > qw) {
#pragma unroll
        for (int kblk = 0; kblk < 2; ++kblk)
#pragma unroll
          for (int r = 0; r < 16; ++r) {
            int kvg = kv0 + kblk * 32 + (r & 3) + 8 * (r >> 2) + 4 * hl;
            sT[kblk][r] = (kvg <= qglob) ? sT[kblk][r] : -3e38f;
          }
      }

      unsigned c0[8], c1[8];
      float ps0 = 0.f, ps1 = 0.f, ps2 = 0.f, ps3 = 0.f;
#pragma unroll
      for (int w2 = 0; w2 < 8; ++w2) {
        float p0 = exp2f(sT[0][2 * w2]);
        float p1 = exp2f(sT[0][2 * w2 + 1]);
        float p2 = exp2f(sT[1][2 * w2]);
        float p3 = exp2f(sT[1][2 * w2 + 1]);
        ps0 += p0; ps1 += p1; ps2 += p2; ps3 += p3;
        c0[w2] = cvt_pk_bf16(p0, p1);
        c1[w2] = cvt_pk_bf16(p2, p3);
      }
      lrun += (ps0 + ps1) + (ps2 + ps3);

      // ---- in-register P redistribution via permlane32_swap (T12) ----
      uint32x4 Wv[4];
#pragma unroll
      for (int kblk = 0; kblk < 2; ++kblk)
#pragma unroll
        for (int ksl = 0; ksl < 2; ++ksl)
#pragma unroll
          for (int al = 0; al < 2; ++al) {
            unsigned cp = kblk ? c1[4 * ksl + al]     : c0[4 * ksl + al];
            unsigned cq = kblk ? c1[4 * ksl + 2 + al] : c0[4 * ksl + 2 + al];
            asm volatile("v_permlane32_swap_b32 %0, %1" : "+v"(cp), "+v"(cq));
            Wv[kblk * 2 + ksl][al]     = cp;
            Wv[kblk * 2 + ksl][al + 2] = cq;
          }

#pragma unroll
      for (int dblk = 0; dblk < 2; ++dblk) {
        bf16x8 aV[4];
        const int r = dblk * 32 + l31;
#pragma unroll
        for (int ks = 0; ks < 4; ++ks)
          aV[ks] = *(const bf16x8*)&vsm[r * 64 + ((ks * 16 + hl * 8) ^ ((r & 7) * 8))];
        __builtin_amdgcn_s_setprio(1);
#pragma unroll
        for (int ks = 0; ks < 4; ++ks)
          oT[dblk] = __builtin_amdgcn_mfma_f32_32x32x16_bf16(
              aV[ks], __builtin_bit_cast(bf16x8, Wv[ks]), oT[dblk], 0, 0, 0);
        __builtin_amdgcn_s_setprio(0);
      }
    }

    __syncthreads();
    float* ex = (float*)KVs + wq3 * 2176 + lane * 34;
    if (p == 1) {
      lrun += __shfl_xor(lrun, 32);
#pragma unroll
      for (int dblk = 0; dblk < 2; ++dblk)
#pragma unroll
        for (int rb = 0; rb < 8; ++rb)
          *(float2*)(ex + dblk * 16 + rb * 2) =
              make_float2(oT[dblk][2 * rb], oT[dblk][2 * rb + 1]);
      ex[32] = lrun;
    }
    __syncthreads();
    if (p == 0) {
      lrun += __shfl_xor(lrun, 32);
      lrun += ex[32];
#pragma unroll
      for (int dblk = 0; dblk < 2; ++dblk)
#pragma unroll
        for (int rb = 0; rb < 8; ++rb) {
          float2 v = *(float2*)(ex + dblk * 16 + rb * 2);
          oT[dblk][2 * rb]     += v.x;
          oT[dblk][2 * rb + 1] += v.y;
        }
      const float inv = 1.0f / fmaxf(lrun, 1e-30f);
#pragma unroll
      for (int dblk = 0; dblk < 2; ++dblk)
#pragma unroll
        for (int rb = 0; rb < 4; ++rb) {
          unsigned u0 = cvt_pk_bf16(oT[dblk][4 * rb]     * inv, oT[dblk][4 * rb + 1] * inv);
          unsigned u1 = cvt_pk_bf16(oT[dblk][4 * rb + 2] * inv, oT[dblk][4 * rb + 3] * inv);
          int d = dblk * 32 + rb * 8 + 4 * hl;
          size_t idx = ((size_t)(b * 2048 + qglob)) * 1024 + h * 64 + d;
          *(uint2*)&Ctx[idx] = make_uint2(u0, u1);
        }
    }
  };

  strip(15 - (int)blockIdx.y);
  strip((int)blockIdx.y);
}

// ---------------------------------------------------------------------------
extern "C" void kernel_launch(void* const* d_in, const int* in_sizes, int n_in,
                              void* d_out, int out_size, void* d_ws, size_t ws_size,
                              hipStream_t stream) {
  const float* q  = (const float*)d_in[0];
  const float* k  = (const float*)d_in[1];
  const float* v  = (const float*)d_in[2];
  const float* wq = (const float*)d_in[3];
  const float* bq = (const float*)d_in[4];
  const float* wk = (const float*)d_in[5];
  const float* bk = (const float*)d_in[6];
  const float* wv = (const float*)d_in[7];
  const float* bv = (const float*)d_in[8];
  const float* wo = (const float*)d_in[9];
  const float* bo = (const float*)d_in[10];
  float* out = (float*)d_out;
  char* ws = (char*)d_ws;

  const size_t MB = 1024 * 1024;
  __bf16* Wqb  = (__bf16*)(ws + 0 * MB);
  __bf16* Wkb  = (__bf16*)(ws + 2 * MB);
  __bf16* Wvb  = (__bf16*)(ws + 4 * MB);
  __bf16* Wob  = (__bf16*)(ws + 6 * MB);
  __bf16* Ctx  = (__bf16*)(ws + 8 * MB);   // 16 MB
  __bf16* Qh   = (__bf16*)(ws + 24 * MB);
  __bf16* Kh   = (__bf16*)(ws + 40 * MB);
  __bf16* Vt   = (__bf16*)(ws + 56 * MB);  // ends at 72 MB

  const int W8 = 1024 * 1024 / 8;

  convert_w4<<<2048, 256, 0, stream>>>(wq, wk, wv, wo, Wqb, Wkb, Wvb, Wob, W8);

  gemm_qkv<<<dim3(64, 8, 3), 256, 0, stream>>>(q, k, v, Wqb, Wkb, Wvb,
                                               bq, bk, bv, Qh, Kh, Vt);

  attn_fwd<<<dim3(64, 8), 512, 0, stream>>>(Qh, Kh, Vt, Ctx);

  gemm_out<<<dim3(64, 8), 256, 0, stream>>>(Ctx, Wob, bo, out);
}

// Round 18
// 197.100 us; speedup vs baseline: 3.8264x; 1.0026x over previous
//
#include <hip/hip_runtime.h>

#define DEVI __device__ __forceinline__

typedef __attribute__((ext_vector_type(8))) __bf16 bf16x8;
typedef __attribute__((ext_vector_type(4))) float f32x4;
typedef __attribute__((ext_vector_type(16))) float f32x16;
typedef __attribute__((ext_vector_type(4))) unsigned uint32x4;

DEVI __bf16 f2bf(float f) {
  unsigned u = __builtin_bit_cast(unsigned, f);
  unsigned r = u + 0x7fffu + ((u >> 16) & 1u);
  unsigned short h = (unsigned short)(r >> 16);
  return __builtin_bit_cast(__bf16, h);
}

DEVI unsigned cvt_pk_bf16(float lo, float hi) {
  unsigned r;
  asm("v_cvt_pk_bf16_f32 %0, %1, %2" : "=v"(r) : "v"(lo), "v"(hi));
  return r;
}

DEVI void load_lds16(const void* g, void* l) {
  __builtin_amdgcn_global_load_lds((__attribute__((address_space(1))) const void*)g,
                                   (__attribute__((address_space(3))) void*)l,
                                   16, 0, 0);
}

// all four 1024x1024 weight matrices in one launch
__global__ void convert_w4(const float* __restrict__ w0, const float* __restrict__ w1,
                           const float* __restrict__ w2, const float* __restrict__ w3,
                           __bf16* __restrict__ o0, __bf16* __restrict__ o1,
                           __bf16* __restrict__ o2, __bf16* __restrict__ o3, int n8) {
  int stride = gridDim.x * blockDim.x;
  for (int i = blockIdx.x * blockDim.x + threadIdx.x; i < 4 * n8; i += stride) {
    int sel = i / n8, j = i - sel * n8;
    const float* in = sel == 0 ? w0 : sel == 1 ? w1 : sel == 2 ? w2 : w3;
    __bf16* out = sel == 0 ? o0 : sel == 1 ? o1 : sel == 2 ? o2 : o3;
    float4 a = ((const float4*)in)[j * 2];
    float4 b = ((const float4*)in)[j * 2 + 1];
    bf16x8 o;
    o[0] = f2bf(a.x); o[1] = f2bf(a.y); o[2] = f2bf(a.z); o[3] = f2bf(a.w);
    o[4] = f2bf(b.x); o[5] = f2bf(b.y); o[6] = f2bf(b.z); o[7] = f2bf(b.w);
    ((bf16x8*)out)[j] = o;
  }
}

// ---------------------------------------------------------------------------
// FUSED QKV projection GEMM (round-17 verified, 197.6us config — unchanged):
// __launch_bounds__(256,4), A fp32 -> regs (T14 reg-staged) -> cvt_pk ->
// swizzled ds_write; W via global_load_lds; 32KB LDS double-buffer.
// SEL 0: Qh bf16 [BH][S][64], PRE-SCALED by CE. SEL 1: Kh. SEL 2: Vt [BH][64][S].
// ---------------------------------------------------------------------------
__global__ __launch_bounds__(256, 4) void gemm_qkv(
    const float* __restrict__ qa, const float* __restrict__ ka, const float* __restrict__ va,
    const __bf16* __restrict__ Wq, const __bf16* __restrict__ Wk, const __bf16* __restrict__ Wv,
    const float* __restrict__ bq, const float* __restrict__ bk, const float* __restrict__ bv,
    __bf16* __restrict__ Qh, __bf16* __restrict__ Kh, __bf16* __restrict__ Vt)
{
  __shared__ __align__(16) __bf16 As[2][128 * 32];
  __shared__ __align__(16) __bf16 Bs[2][128 * 32];
  const int sel = blockIdx.z;
  const float* A = sel == 0 ? qa : sel == 1 ? ka : va;
  const __bf16* W = sel == 0 ? Wq : sel == 1 ? Wk : Wv;
  const float* bias = sel == 0 ? bq : sel == 1 ? bk : bv;
  __bf16* outp = sel == 0 ? Qh : sel == 1 ? Kh : Vt;
  const bool vmode = (sel == 2);
  const float osc = (sel == 0) ? 0.18033688f : 1.0f; // CE = (1/8)*log2(e) into Q

  const int tid = threadIdx.x;
  const int lane = tid & 63;
  const int ln = lane & 15, g = lane >> 4;
  const int w = tid >> 6;
  const int wr = w >> 1, wc = w & 1;
  const int id = blockIdx.y * 64 + blockIdx.x;
  const int bx = 8 * (id & 7) + ((id >> 3) & 7);     // XCD swizzle
  const int by = id >> 6;
  const int row0 = bx * 128, col0 = by * 128;

  const int ar = tid >> 1, ah = tid & 1;   // A staging: row (0..127), half (16 floats)
  const int axr = (ar >> 1) & 3;           // row swizzle term

  f32x4 acc[4][4] = {};
  float4 fA[4];

  auto issueA = [&](int kt) {              // 64B fp32 per thread -> regs
    const float4* src = (const float4*)&A[(size_t)(row0 + ar) * 1024 + kt * 32 + ah * 16];
#pragma unroll
    for (int j = 0; j < 4; ++j) fA[j] = src[j];
  };
  auto issueW = [&](int buf, int kt) {     // 2x gload_lds per thread
#pragma unroll
    for (int i = 0; i < 2; ++i) {
      int c = tid + 256 * i;
      int r = c >> 2, sl = c & 3;
      int so = 8 * (sl ^ ((r >> 1) & 3));  // inverse-swizzled source slot
      load_lds16(&W[(size_t)(col0 + r) * 1024 + kt * 32 + so], &Bs[buf][c * 8]);
    }
  };
  auto writeA = [&](int buf) {             // cvt + swizzled ds_write_b128 x2
#pragma unroll
    for (int j = 0; j < 2; ++j) {
      uint32x4 o;
      o[0] = cvt_pk_bf16(fA[2 * j].x, fA[2 * j].y);
      o[1] = cvt_pk_bf16(fA[2 * j].z, fA[2 * j].w);
      o[2] = cvt_pk_bf16(fA[2 * j + 1].x, fA[2 * j + 1].y);
      o[3] = cvt_pk_bf16(fA[2 * j + 1].z, fA[2 * j + 1].w);
      int s = 2 * ah + j;                  // source 16B slot
      *(uint32x4*)&As[buf][ar * 32 + (s ^ axr) * 8] = o;   // LDS slot = s ^ x
    }
  };
  auto compute = [&](int buf) {
    const __bf16* as = As[buf];
    const __bf16* bs = Bs[buf];
    bf16x8 aF[4], bF[4];
#pragma unroll
    for (int mi = 0; mi < 4; ++mi) {
      int r = wr * 64 + mi * 16 + ln;
      aF[mi] = *(const bf16x8*)&as[r * 32 + ((g * 8) ^ (((r >> 1) & 3) * 8))];
    }
#pragma unroll
    for (int ni = 0; ni < 4; ++ni) {
      int r = wc * 64 + ni * 16 + ln;
      bF[ni] = *(const bf16x8*)&bs[r * 32 + ((g * 8) ^ (((r >> 1) & 3) * 8))];
    }
    __builtin_amdgcn_s_setprio(1);
#pragma unroll
    for (int mi = 0; mi < 4; ++mi)
#pragma unroll
      for (int ni = 0; ni < 4; ++ni)
        acc[mi][ni] = __builtin_amdgcn_mfma_f32_16x16x32_bf16(aF[mi], bF[ni], acc[mi][ni], 0, 0, 0);
    __builtin_amdgcn_s_setprio(0);
  };

  // prologue: stage tile 0
  issueA(0); issueW(0, 0);
  writeA(0);                               // compiler waits for fA loads
  __syncthreads();                         // drains W(0) gload_lds, publishes buf0
#pragma unroll 1
  for (int kt = 0; kt < 32; ++kt) {
    const int cur = kt & 1, nxt = cur ^ 1;
    if (kt + 1 < 32) { issueA(kt + 1); issueW(nxt, kt + 1); }   // latency under compute
    compute(cur);
    if (kt + 1 < 32) writeA(nxt);          // regs -> LDS (other buffer)
    __syncthreads();                       // drain + publish buf nxt
  }

#pragma unroll
  for (int ni = 0; ni < 4; ++ni) {
    int n = col0 + wc * 64 + ni * 16 + ln;
    float bv = bias[n];
#pragma unroll
    for (int mi = 0; mi < 4; ++mi) {
#pragma unroll
      for (int i = 0; i < 4; ++i) {
        int m = row0 + wr * 64 + mi * 16 + g * 4 + i;   // C-layout: row=(l>>4)*4+i, col=l&15
        float val = (acc[mi][ni][i] + bv) * osc;
        int b = m >> 11, s = m & 2047, h = n >> 6, d = n & 63;
        size_t idx = vmode
          ? ((size_t)((b * 16 + h) * 64 + d) * 2048 + s)
          : ((size_t)((b * 16 + h) * 2048 + s) * 64 + d);
        outp[idx] = f2bf(val);
      }
    }
  }
}

// ---------------------------------------------------------------------------
// Output GEMM (bf16 A = Ctx): depth-2 counted-vmcnt, fp32 out. ONLY CHANGE
// THIS ROUND: __launch_bounds__(256,2) -> (256,3). 48KB LDS admits exactly
// 3 blocks/CU (144<=160); VGPR budget at 3 waves/SIMD = 170 >> ~110 needed,
// so no spill possible (unlike round-15's (256,5) on qkv).
// ---------------------------------------------------------------------------
__global__ __launch_bounds__(256, 3) void gemm_out(
    const __bf16* __restrict__ A, const __bf16* __restrict__ W,
    const float* __restrict__ bias, float* __restrict__ outp)
{
  __shared__ __bf16 As[3][128 * 32];
  __shared__ __bf16 Bs[3][128 * 32];
  const int tid = threadIdx.x;
  const int lane = tid & 63;
  const int ln = lane & 15, g = lane >> 4;
  const int w = tid >> 6;
  const int wr = w >> 1, wc = w & 1;
  const int id = blockIdx.y * 64 + blockIdx.x;
  const int bx = 8 * (id & 7) + ((id >> 3) & 7);
  const int by = id >> 6;
  const int row0 = bx * 128, col0 = by * 128;

  f32x4 acc[4][4] = {};

  auto stage = [&](int buf, int kt) {
    const int k0 = kt * 32;
#pragma unroll
    for (int i = 0; i < 2; ++i) {
      int c = tid + 256 * i;
      int r = c >> 2, sl = c & 3;
      int so = 8 * (sl ^ ((r >> 1) & 3));
      load_lds16(&A[(size_t)(row0 + r) * 1024 + k0 + so], &As[buf][c * 8]);
      load_lds16(&W[(size_t)(col0 + r) * 1024 + k0 + so], &Bs[buf][c * 8]);
    }
  };

  auto compute = [&](int buf) {
    const __bf16* as = As[buf];
    const __bf16* bs = Bs[buf];
    bf16x8 aF[4], bF[4];
#pragma unroll
    for (int mi = 0; mi < 4; ++mi) {
      int r = wr * 64 + mi * 16 + ln;
      aF[mi] = *(const bf16x8*)&as[r * 32 + ((g * 8) ^ (((r >> 1) & 3) * 8))];
    }
#pragma unroll
    for (int ni = 0; ni < 4; ++ni) {
      int r = wc * 64 + ni * 16 + ln;
      bF[ni] = *(const bf16x8*)&bs[r * 32 + ((g * 8) ^ (((r >> 1) & 3) * 8))];
    }
    __builtin_amdgcn_s_setprio(1);
#pragma unroll
    for (int mi = 0; mi < 4; ++mi)
#pragma unroll
      for (int ni = 0; ni < 4; ++ni)
        acc[mi][ni] = __builtin_amdgcn_mfma_f32_16x16x32_bf16(aF[mi], bF[ni], acc[mi][ni], 0, 0, 0);
    __builtin_amdgcn_s_setprio(0);
  };

  stage(0, 0);
  stage(1, 1);
#pragma unroll 1
  for (int kt = 0; kt < 31; ++kt) {
    asm volatile("s_waitcnt vmcnt(4)" ::: "memory");
    __builtin_amdgcn_s_barrier();
    asm volatile("" ::: "memory");
    if (kt + 2 < 32) stage((kt + 2) % 3, kt + 2);
    compute(kt % 3);
  }
  asm volatile("s_waitcnt vmcnt(0)" ::: "memory");
  __builtin_amdgcn_s_barrier();
  asm volatile("" ::: "memory");
  compute(31 % 3);

#pragma unroll
  for (int ni = 0; ni < 4; ++ni) {
    int n = col0 + wc * 64 + ni * 16 + ln;
    float bv = bias[n];
#pragma unroll
    for (int mi = 0; mi < 4; ++mi) {
#pragma unroll
      for (int i = 0; i < 4; ++i) {
        int m = row0 + wr * 64 + mi * 16 + g * 4 + i;
        outp[(size_t)m * 1024 + n] = acc[mi][ni][i] + bv;
      }
    }
  }
}

// ---------------------------------------------------------------------------
// Causal flash attention (round-14/17 verified, unchanged): 32x32x16 MFMA,
// swapped-operand, P in registers, exp2-direct softmax (CE pre-folded into
// Qh), permlane32_swap P-redistribution, split-KV 8-wave blocks,
// work-balanced strips.
// ---------------------------------------------------------------------------
__global__ __launch_bounds__(512, 4) void attn_fwd(
    const __bf16* __restrict__ Qh, const __bf16* __restrict__ Kh,
    const __bf16* __restrict__ Vt, __bf16* __restrict__ Ctx)
{
  __shared__ __bf16 KVs[8][64 * 64];                 // 64 KB

  const int tid = threadIdx.x;
  const int lane = tid & 63;
  const int l31 = lane & 31, hl = lane >> 5;
  const int w = tid >> 6;                            // 0..7
  const int wq3 = w & 3, p = w >> 2;                 // q-strip quarter, kv parity
  const int bh = blockIdx.x;
  const int b = bh >> 4, h = bh & 15;

  auto stagePair = [&](int tp) {
    const int base = 2 * (tp & 1);
    const int c = tid;
    const int r = c >> 3, sl = c & 7;
    const int so = 8 * (sl ^ (r & 7));
#pragma unroll
    for (int i = 0; i < 2; ++i) {
      const int kv0 = (2 * tp + i) * 64, s = base + i;
      load_lds16(&Kh[((size_t)bh * 2048 + kv0 + r) * 64 + so], &KVs[s][c * 8]);
      load_lds16(&Vt[((size_t)bh * 64 + r) * 2048 + kv0 + so], &KVs[4 + s][c * 8]);
    }
  };

  auto strip = [&](int qb) {
    const int q0 = qb * 128;
    const int qw = q0 + wq3 * 32;
    const int qglob = qw + l31;
    const int np = qb + 1;

    bf16x8 qF[4];
#pragma unroll
    for (int ds = 0; ds < 4; ++ds)
      qF[ds] = *(const bf16x8*)&Qh[((size_t)bh * 2048 + qglob) * 64 + ds * 16 + hl * 8];

    f32x16 oT[2] = {};
    float lrun = 0.f;

    __syncthreads();
    stagePair(0);
    for (int tp = 0; tp < np; ++tp) {
      __syncthreads();
      if (tp + 1 < np) stagePair(tp + 1);
      const int kv0 = (2 * tp + p) * 64;
      if (kv0 > qw + 31) continue;
      const __bf16* ksm = KVs[2 * (tp & 1) + p];
      const __bf16* vsm = KVs[4 + 2 * (tp & 1) + p];

      f32x16 sT[2] = {};
#pragma unroll
      for (int kblk = 0; kblk < 2; ++kblk) {
        bf16x8 aK[4];
        const int r = kblk * 32 + l31;
#pragma unroll
        for (int ds = 0; ds < 4; ++ds)
          aK[ds] = *(const bf16x8*)&ksm[r * 64 + ((ds * 16 + hl * 8) ^ ((r & 7) * 8))];
        __builtin_amdgcn_s_setprio(1);
#pragma unroll
        for (int ds = 0; ds < 4; ++ds)
          sT[kblk] = __builtin_amdgcn_mfma_f32_32x32x16_bf16(aK[ds], qF[ds], sT[kblk], 0, 0, 0);
        __builtin_amdgcn_s_setprio(0);
      }

      if (kv0 + 63 > qw) {
#pragma unroll
        for (int kblk = 0; kblk < 2; ++kblk)
#pragma unroll
          for (int r = 0; r < 16; ++r) {
            int kvg = kv0 + kblk * 32 + (r & 3) + 8 * (r >> 2) + 4 * hl;
            sT[kblk][r] = (kvg <= qglob) ? sT[kblk][r] : -3e38f;
          }
      }

      unsigned c0[8], c1[8];
      float ps0 = 0.f, ps1 = 0.f, ps2 = 0.f, ps3 = 0.f;
#pragma unroll
      for (int w2 = 0; w2 < 8; ++w2) {
        float p0 = exp2f(sT[0][2 * w2]);
        float p1 = exp2f(sT[0][2 * w2 + 1]);
        float p2 = exp2f(sT[1][2 * w2]);
        float p3 = exp2f(sT[1][2 * w2 + 1]);
        ps0 += p0; ps1 += p1; ps2 += p2; ps3 += p3;
        c0[w2] = cvt_pk_bf16(p0, p1);
        c1[w2] = cvt_pk_bf16(p2, p3);
      }
      lrun += (ps0 + ps1) + (ps2 + ps3);

      // ---- in-register P redistribution via permlane32_swap (T12) ----
      uint32x4 Wv[4];
#pragma unroll
      for (int kblk = 0; kblk < 2; ++kblk)
#pragma unroll
        for (int ksl = 0; ksl < 2; ++ksl)
#pragma unroll
          for (int al = 0; al < 2; ++al) {
            unsigned cp = kblk ? c1[4 * ksl + al]     : c0[4 * ksl + al];
            unsigned cq = kblk ? c1[4 * ksl + 2 + al] : c0[4 * ksl + 2 + al];
            asm volatile("v_permlane32_swap_b32 %0, %1" : "+v"(cp), "+v"(cq));
            Wv[kblk * 2 + ksl][al]     = cp;
            Wv[kblk * 2 + ksl][al + 2] = cq;
          }

#pragma unroll
      for (int dblk = 0; dblk < 2; ++dblk) {
        bf16x8 aV[4];
        const int r = dblk * 32 + l31;
#pragma unroll
        for (int ks = 0; ks < 4; ++ks)
          aV[ks] = *(const bf16x8*)&vsm[r * 64 + ((ks * 16 + hl * 8) ^ ((r & 7) * 8))];
        __builtin_amdgcn_s_setprio(1);
#pragma unroll
        for (int ks = 0; ks < 4; ++ks)
          oT[dblk] = __builtin_amdgcn_mfma_f32_32x32x16_bf16(
              aV[ks], __builtin_bit_cast(bf16x8, Wv[ks]), oT[dblk], 0, 0, 0);
        __builtin_amdgcn_s_setprio(0);
      }
    }

    __syncthreads();
    float* ex = (float*)KVs + wq3 * 2176 + lane * 34;
    if (p == 1) {
      lrun += __shfl_xor(lrun, 32);
#pragma unroll
      for (int dblk = 0; dblk < 2; ++dblk)
#pragma unroll
        for (int rb = 0; rb < 8; ++rb)
          *(float2*)(ex + dblk * 16 + rb * 2) =
              make_float2(oT[dblk][2 * rb], oT[dblk][2 * rb + 1]);
      ex[32] = lrun;
    }
    __syncthreads();
    if (p == 0) {
      lrun += __shfl_xor(lrun, 32);
      lrun += ex[32];
#pragma unroll
      for (int dblk = 0; dblk < 2; ++dblk)
#pragma unroll
        for (int rb = 0; rb < 8; ++rb) {
          float2 v = *(float2*)(ex + dblk * 16 + rb * 2);
          oT[dblk][2 * rb]     += v.x;
          oT[dblk][2 * rb + 1] += v.y;
        }
      const float inv = 1.0f / fmaxf(lrun, 1e-30f);
#pragma unroll
      for (int dblk = 0; dblk < 2; ++dblk)
#pragma unroll
        for (int rb = 0; rb < 4; ++rb) {
          unsigned u0 = cvt_pk_bf16(oT[dblk][4 * rb]     * inv, oT[dblk][4 * rb + 1] * inv);
          unsigned u1 = cvt_pk_bf16(oT[dblk][4 * rb + 2] * inv, oT[dblk][4 * rb + 3] * inv);
          int d = dblk * 32 + rb * 8 + 4 * hl;
          size_t idx = ((size_t)(b * 2048 + qglob)) * 1024 + h * 64 + d;
          *(uint2*)&Ctx[idx] = make_uint2(u0, u1);
        }
    }
  };

  strip(15 - (int)blockIdx.y);
  strip((int)blockIdx.y);
}

// ---------------------------------------------------------------------------
extern "C" void kernel_launch(void* const* d_in, const int* in_sizes, int n_in,
                              void* d_out, int out_size, void* d_ws, size_t ws_size,
                              hipStream_t stream) {
  const float* q  = (const float*)d_in[0];
  const float* k  = (const float*)d_in[1];
  const float* v  = (const float*)d_in[2];
  const float* wq = (const float*)d_in[3];
  const float* bq = (const float*)d_in[4];
  const float* wk = (const float*)d_in[5];
  const float* bk = (const float*)d_in[6];
  const float* wv = (const float*)d_in[7];
  const float* bv = (const float*)d_in[8];
  const float* wo = (const float*)d_in[9];
  const float* bo = (const float*)d_in[10];
  float* out = (float*)d_out;
  char* ws = (char*)d_ws;

  const size_t MB = 1024 * 1024;
  __bf16* Wqb  = (__bf16*)(ws + 0 * MB);
  __bf16* Wkb  = (__bf16*)(ws + 2 * MB);
  __bf16* Wvb  = (__bf16*)(ws + 4 * MB);
  __bf16* Wob  = (__bf16*)(ws + 6 * MB);
  __bf16* Ctx  = (__bf16*)(ws + 8 * MB);   // 16 MB
  __bf16* Qh   = (__bf16*)(ws + 24 * MB);
  __bf16* Kh   = (__bf16*)(ws + 40 * MB);
  __bf16* Vt   = (__bf16*)(ws + 56 * MB);  // ends at 72 MB

  const int W8 = 1024 * 1024 / 8;

  convert_w4<<<2048, 256, 0, stream>>>(wq, wk, wv, wo, Wqb, Wkb, Wvb, Wob, W8);

  gemm_qkv<<<dim3(64, 8, 3), 256, 0, stream>>>(q, k, v, Wqb, Wkb, Wvb,
                                               bq, bk, bv, Qh, Kh, Vt);

  attn_fwd<<<dim3(64, 8), 512, 0, stream>>>(Qh, Kh, Vt, Ctx);

  gemm_out<<<dim3(64, 8), 256, 0, stream>>>(Ctx, Wob, bo, out);
}